// Round 4
// baseline (2923.292 us; speedup 1.0000x reference)
//
#include <hip/hip_runtime.h>
#include <stdint.h>

// ---- problem constants ----
#define T_DIM 100
#define B_DIM 1000
#define E_DIM 512
#define D_DIM 256
#define L_DIM 4
#define M_TOK (T_DIM * B_DIM)   // 100000 tokens
#define M_PAD 100096             // 782 * 128 (GEMM M padding; pad rows zeroed)
#define K_DIM 512
#define MT128 782                // m-tiles of 128 rows

typedef unsigned short u16;
typedef __bf16 bf16x8 __attribute__((ext_vector_type(8)));
typedef float f32x4 __attribute__((ext_vector_type(4)));
typedef unsigned short ushort8 __attribute__((ext_vector_type(8)));
typedef unsigned short ushort4v __attribute__((ext_vector_type(4)));

__device__ __forceinline__ u16 f2bf(float f) {
  unsigned int u = __builtin_bit_cast(unsigned int, f);
  u += 0x7fffu + ((u >> 16) & 1u);
  return (u16)(u >> 16);
}
__device__ __forceinline__ float bf2f(u16 h) {
  unsigned int u = ((unsigned int)h) << 16;
  return __builtin_bit_cast(float, u);
}

__device__ __forceinline__ void gld16(const u16* g, u16* l) {
  __builtin_amdgcn_global_load_lds(
      (const __attribute__((address_space(1))) unsigned int*)g,
      (__attribute__((address_space(3))) unsigned int*)l, 16, 0, 0);
}

// ---- transpose + cast weights: in fp32 (S, R, C) -> out bf16 (S, C, R) ----
// perm4: output-row permutation n' = (n&255)*4 + (n>>8)  [gate-major -> d-major]
// so GEMM columns become (d, gate) interleaved; sru_scan then reads one
// coalesced ushort4 per (t,b,d) step instead of 4 strided scalar loads.
__global__ void transpose_cast(const float* __restrict__ in, u16* __restrict__ out,
                               int R, int C, int perm4) {
  __shared__ float t[32][33];
  const int s = blockIdx.z;
  const float* ib = in + (size_t)s * R * C;
  u16* ob = out + (size_t)s * R * C;
  const int c0 = blockIdx.x * 32, r0 = blockIdx.y * 32;
  const int tx = threadIdx.x, ty = threadIdx.y;  // (32, 8)
#pragma unroll
  for (int j = 0; j < 4; ++j)
    t[ty + j * 8][tx] = ib[(size_t)(r0 + ty + j * 8) * C + c0 + tx];
  __syncthreads();
#pragma unroll
  for (int j = 0; j < 4; ++j) {
    const int cc = c0 + ty + j * 8;
    const int n = perm4 ? ((cc & 255) * 4 + (cc >> 8)) : cc;
    ob[(size_t)n * R + r0 + tx] = f2bf(t[tx][ty + j * 8]);
  }
}

// ---- zero GEMM pad rows of xl (rows M_TOK..M_PAD-1), once per call ----
__global__ __launch_bounds__(256) void zero_pad(u16* __restrict__ xl) {
  const int i = blockIdx.x * 256 + threadIdx.x;  // 6144 lanes x 8 elems
  ushort8 z = {0, 0, 0, 0, 0, 0, 0, 0};
  *(ushort8*)(xl + (size_t)M_TOK * 512 + (size_t)i * 8) = z;
}

// ---- fused LayerNorm + cast to bf16 (rows < M_TOK only) ----
template <typename TI>
__global__ __launch_bounds__(256) void ln_cast_kernel(
    const TI* __restrict__ x, const float* __restrict__ g,
    const float* __restrict__ b, u16* __restrict__ out) {
  const int wid = threadIdx.x >> 6, lane = threadIdx.x & 63;
  const int row = blockIdx.x * 4 + wid;  // < M_TOK
  float xe[8];
  if constexpr (sizeof(TI) == 4) {
    const float* xr = (const float*)x + (size_t)row * E_DIM + lane * 8;
    const float4 a = *(const float4*)xr;
    const float4 c = *(const float4*)(xr + 4);
    xe[0] = a.x; xe[1] = a.y; xe[2] = a.z; xe[3] = a.w;
    xe[4] = c.x; xe[5] = c.y; xe[6] = c.z; xe[7] = c.w;
  } else {
    const u16* xr = (const u16*)x + (size_t)row * E_DIM + lane * 8;
    const ushort8 hv = *(const ushort8*)xr;
#pragma unroll
    for (int u = 0; u < 8; ++u) xe[u] = bf2f(hv[u]);
  }
  float s = 0.f, q = 0.f;
#pragma unroll
  for (int u = 0; u < 8; ++u) { s += xe[u]; q += xe[u] * xe[u]; }
#pragma unroll
  for (int off = 32; off; off >>= 1) {
    s += __shfl_xor(s, off, 64);
    q += __shfl_xor(q, off, 64);
  }
  const float mean = s * (1.0f / 512.0f);
  const float var = q * (1.0f / 512.0f) - mean * mean;
  const float rstd = rsqrtf(var + 1e-5f);
  const float4 g0 = *(const float4*)(g + lane * 8);
  const float4 g1 = *(const float4*)(g + lane * 8 + 4);
  const float4 b0 = *(const float4*)(b + lane * 8);
  const float4 b1v = *(const float4*)(b + lane * 8 + 4);
  float ge[8] = {g0.x, g0.y, g0.z, g0.w, g1.x, g1.y, g1.z, g1.w};
  float be[8] = {b0.x, b0.y, b0.z, b0.w, b1v.x, b1v.y, b1v.z, b1v.w};
  ushort8 o;
#pragma unroll
  for (int u = 0; u < 8; ++u)
    o[u] = f2bf((xe[u] - mean) * rstd * ge[u] + be[u]);
  *(ushort8*)(out + (size_t)row * E_DIM + lane * 8) = o;
}

// ---- 128x128 bf16 MFMA GEMM: C[z] = A @ B[z]^T ----
// Round-3 structure (4 waves, 64x64/wave, XCD m-tile ownership, chunk-XOR
// LDS swizzle for A) with B-DIRECT fragments:
//   B is small (<=2 MB) and L2-resident per XCD; each B-fragment is 16
//   contiguous bytes in global memory at the exact pre-swizzle staging
//   address, so we load B straight into MFMA operands and cut LDS traffic
//   in half (no B staging writes, no B ds_reads).
// Per K-tile order (VMEM queue discipline):
//   1) af ds_reads (lgkm, order-free)
//   2) bcur[4] global_load_dwordx4   <- the 4 OLDEST VMEM ops
//   3) sched_barrier(0)              <- pin stage below the B-loads
//   4) STAGE_A(t+1) (2 global_load_lds, youngest)
//   5) MFMA x16: compiler emits vmcnt(2) (retire B, keep A in flight)
//   6) vmcnt(0) (only the 2 A-glds remain, issued ~1 tile ago) + barrier
// A dbuf safety: STAGE_A(t+1) writes As[(t+1)&1], last read at t-1; those
// ds_reads completed before t-1's MFMAs which precede the end-of-(t-1)
// barrier; STAGE_A(t+1) is issued after it.
__global__ __launch_bounds__(256, 4) void gemm_bf16(
    const u16* __restrict__ A, const u16* __restrict__ B, u16* __restrict__ C,
    int N, int nc_shift, int ncol_shift) {
  __shared__ u16 As[2][4096];  // 16 KiB: [buf][128 rows x 32 cols swizzled]

  const int bid = blockIdx.x;
  const int xcd = bid & 7;
  const int kk = bid >> 3;
  const int cix = kk & ((1 << nc_shift) - 1);   // (z, n-tile) combined
  const int jj = kk >> nc_shift;
  const int mt = xcd + 8 * jj;
  if (mt >= MT128) return;  // whole block exits before any barrier
  const int z = cix >> ncol_shift;
  const int n0 = (cix & ((1 << ncol_shift) - 1)) << 7;

  const int tid = threadIdx.x;
  const int wave = tid >> 6, lane = tid & 63;
  const int wm = wave >> 1, wn = wave & 1;

  // A staging: lane l covers row (l>>2); fetches global chunk
  // (l&3)^((l>>3)&3) so linear LDS holds the swizzled layout.
  const int r_l = lane >> 2;
  const int c_ld = (lane & 3) ^ ((lane >> 3) & 3);
  const u16* Ag = A + ((size_t)mt * 128 + wave * 32 + r_l) * K_DIM + c_ld * 8;

  auto STAGE_A = [&](int t) {
    u16* al = &As[t & 1][wave * 1024];
    const u16* ag = Ag + t * 32;
    gld16(ag, al);
    gld16(ag + 16 * K_DIM, al + 512);
  };

  const int rA = lane & 15;
  const int ch = lane >> 4;
  const int sw = (ch ^ ((rA >> 1) & 3)) * 8;  // swizzled k-chunk (A reads)
  const int offA = (wm * 64 + rA) * 32 + sw;
  // B-direct fragment base: lane reads B^T[n0+wn*64+ni*16+rA][kt+ch*8 ..+7]
  const u16* Bg = B + ((size_t)z * N + n0 + wn * 64 + rA) * K_DIM + ch * 8;

  STAGE_A(0);

  f32x4 acc[4][4] = {};

  asm volatile("s_waitcnt vmcnt(0)" ::: "memory");  // tile-0 A staged (own)
  asm volatile("s_barrier" ::: "memory");           // all waves' A landed

#pragma unroll
  for (int t = 0; t < 16; ++t) {
    const u16* Ab = As[t & 1];
    bf16x8 af[4], bcur[4];
#pragma unroll
    for (int mi = 0; mi < 4; ++mi)
      af[mi] = *(const bf16x8*)&Ab[offA + mi * 512];
#pragma unroll
    for (int ni = 0; ni < 4; ++ni)
      bcur[ni] = *(const bf16x8*)(Bg + (size_t)ni * 16 * K_DIM + t * 32);
    __builtin_amdgcn_sched_barrier(0);  // B-loads stay OLDER than the stage
    if (t < 15) STAGE_A(t + 1);
#pragma unroll
    for (int mi = 0; mi < 4; ++mi)
#pragma unroll
      for (int ni = 0; ni < 4; ++ni)
        acc[mi][ni] = __builtin_amdgcn_mfma_f32_16x16x32_bf16(
            af[mi], bcur[ni], acc[mi][ni], 0, 0, 0);
    if (t < 15) {
      // only the 2 A-glds of t+1 remain in flight here: exact counted wait
      asm volatile("s_waitcnt vmcnt(0)" ::: "memory");
      asm volatile("s_barrier" ::: "memory");
    }
  }

  // epilogue: verified C/D mapping (col=lane&15, row=(lane>>4)*4+r)
  u16* Cb = C + (size_t)z * M_PAD * N;
  const int rr = (lane >> 4) * 4;
  const int cc = lane & 15;
#pragma unroll
  for (int mi = 0; mi < 4; ++mi) {
#pragma unroll
    for (int ni = 0; ni < 4; ++ni) {
      const size_t row = (size_t)mt * 128 + wm * 64 + mi * 16 + rr;
      const int col = n0 + wn * 64 + ni * 16 + cc;
#pragma unroll
      for (int r = 0; r < 4; ++r)
        Cb[(row + r) * N + col] = f2bf(acc[mi][ni][r]);
    }
  }
}

// ---- SRU elementwise recurrence, one thread per (dir, b, d); bf16 out ----
// U columns are (d, gate) interleaved; one aligned 8 B ushort4 per step.
// Next-step gates are prefetched into registers before the serial sigmoid
// chain of the current step, hiding HBM latency in the dependence chain.
__global__ __launch_bounds__(256) void sru_scan(const u16* __restrict__ U,
                                                const float* __restrict__ v,
                                                const float* __restrict__ bb,
                                                u16* __restrict__ xout) {
  const int d = threadIdx.x;       // 0..255
  const int b = blockIdx.x;        // 0..999
  const int dir = blockIdx.y;      // 0..1
  const float vf = v[(dir * 2 + 0) * 256 + d];
  const float vr = v[(dir * 2 + 1) * 256 + d];
  const float bf = bb[(dir * 2 + 0) * 256 + d];
  const float br = bb[(dir * 2 + 1) * 256 + d];
  const u16* Ud = U + (size_t)dir * M_PAD * 1024;
  float c = 0.f;
  const int t0 = dir ? (T_DIM - 1) : 0;
  const long step = dir ? -(long)(B_DIM * 1024) : (long)(B_DIM * 1024);
  const size_t base0 = ((size_t)t0 * B_DIM + b) * 1024 + d * 4;
  ushort4v uv = *(const ushort4v*)(Ud + base0);
  for (int s = 0; s < T_DIM; ++s) {
    ushort4v nx = uv;
    if (s + 1 < T_DIM)
      nx = *(const ushort4v*)(Ud + (size_t)((long)base0 + step * (s + 1)));
    const int t = dir ? (T_DIM - 1 - s) : s;
    const float u0 = bf2f(uv.x);
    const float u1 = bf2f(uv.y);
    const float u2 = bf2f(uv.z);
    const float u3 = bf2f(uv.w);
    const float f = 1.f / (1.f + __expf(-(u1 + vf * c + bf)));
    c = f * c + (1.f - f) * u0;
    const float r = 1.f / (1.f + __expf(-(u2 + vr * c + br)));
    const float h = r * c + (1.f - r) * u3;
    xout[((size_t)t * B_DIM + b) * 512 + dir * 256 + d] = f2bf(h);
    uv = nx;
  }
}

// ---- head: bias + BN(eval) + ReLU + W2 + log_softmax, one wave per token ----
__global__ __launch_bounds__(256) void head_kernel(
    const u16* __restrict__ h, const float* __restrict__ b1,
    const float* __restrict__ bn_g, const float* __restrict__ bn_b,
    const float* __restrict__ bn_mean, const float* __restrict__ bn_var,
    const float* __restrict__ W2, const float* __restrict__ b2,
    float* __restrict__ out) {
  const int wid = threadIdx.x >> 6, lane = threadIdx.x & 63;
  const int row = blockIdx.x * 4 + wid;  // < 100000 (grid=25000)
  const u16* hr = h + (size_t)row * E_DIM + lane * 8;
  const ushort8 hv = *(const ushort8*)hr;
  float s0 = 0.f, s1 = 0.f, s2 = 0.f, s3 = 0.f;
  const int j0 = lane * 8;
#pragma unroll
  for (int u = 0; u < 8; ++u) {
    const int j = j0 + u;
    const float hb = bf2f(hv[u]) + b1[j];
    float hn = (hb - bn_mean[j]) * rsqrtf(bn_var[j] + 1e-5f) * bn_g[j] + bn_b[j];
    hn = fmaxf(hn, 0.f);
    const float4 w = *(const float4*)(W2 + j * 4);
    s0 += hn * w.x; s1 += hn * w.y; s2 += hn * w.z; s3 += hn * w.w;
  }
#pragma unroll
  for (int off = 32; off; off >>= 1) {
    s0 += __shfl_xor(s0, off, 64);
    s1 += __shfl_xor(s1, off, 64);
    s2 += __shfl_xor(s2, off, 64);
    s3 += __shfl_xor(s3, off, 64);
  }
  if (lane == 0) {
    const float4 bv = *(const float4*)b2;
    const float l0 = s0 + bv.x, l1 = s1 + bv.y, l2 = s2 + bv.z, l3 = s3 + bv.w;
    const float mx = fmaxf(fmaxf(l0, l1), fmaxf(l2, l3));
    const float lse =
        mx + logf(__expf(l0 - mx) + __expf(l1 - mx) + __expf(l2 - mx) + __expf(l3 - mx));
    float4 o = {l0 - lse, l1 - lse, l2 - lse, l3 - lse};
    *(float4*)(out + (size_t)row * 4) = o;
  }
}

extern "C" void kernel_launch(void* const* d_in, const int* in_sizes, int n_in,
                              void* d_out, int out_size, void* d_ws, size_t ws_size,
                              hipStream_t stream) {
  const float* sentence = (const float*)d_in[0];
  const float* sru_W = (const float*)d_in[1];
  const float* sru_v = (const float*)d_in[2];
  const float* sru_b = (const float*)d_in[3];
  const float* ln_g = (const float*)d_in[4];
  const float* ln_b = (const float*)d_in[5];
  const float* W1 = (const float*)d_in[6];
  const float* b1 = (const float*)d_in[7];
  const float* bn_g = (const float*)d_in[8];
  const float* bn_b = (const float*)d_in[9];
  const float* bn_mean = (const float*)d_in[10];
  const float* bn_var = (const float*)d_in[11];
  const float* W2 = (const float*)d_in[12];
  const float* b2 = (const float*)d_in[13];

  // workspace layout (~624 MB)
  char* ws = (char*)d_ws;
  const size_t XL_OFF = 0;                                   // bf16 xl: 102,498,304
  const size_t X_OFF = XL_OFF + (size_t)M_PAD * 512 * 2;     // bf16 x:  102,400,000
  const size_t U_OFF = X_OFF + (size_t)M_TOK * 512 * 2;      // bf16 U:  409,993,216
  const size_t WT_OFF = U_OFF + (size_t)2 * M_PAD * 1024 * 2;   // bf16 WT: 8,388,608
  const size_t W1T_OFF = WT_OFF + (size_t)8 * 512 * 1024 * 2;   // bf16 W1T: 524,288
  u16* xl = (u16*)(ws + XL_OFF);
  u16* x_buf = (u16*)(ws + X_OFF);
  u16* U = (u16*)(ws + U_OFF);
  u16* WT = (u16*)(ws + WT_OFF);
  u16* W1T = (u16*)(ws + W1T_OFF);
  u16* hbuf = U;  // head GEMM output aliases U (dead by then)

  // weights -> bf16 transposed (N, K); sru weights N-permuted to (d,gate);
  // zero xl pad rows once
  transpose_cast<<<dim3(32, 16, 8), dim3(32, 8), 0, stream>>>(sru_W, WT, 512, 1024, 1);
  transpose_cast<<<dim3(16, 16, 1), dim3(32, 8), 0, stream>>>(W1, W1T, 512, 512, 0);
  zero_pad<<<24, 256, 0, stream>>>(xl);

  for (int l = 0; l < L_DIM; ++l) {
    if (l == 0)
      ln_cast_kernel<float><<<M_TOK / 4, 256, 0, stream>>>(
          sentence, ln_g, ln_b, xl);
    else
      ln_cast_kernel<u16><<<M_TOK / 4, 256, 0, stream>>>(
          x_buf, ln_g + l * 512, ln_b + l * 512, xl);
    // 8 xcd x 16 (z,n) x 98 m-slots = 12544 blocks (32 idle-guarded)
    gemm_bf16<<<dim3(8 * 16 * 98), 256, 0, stream>>>(
        xl, WT + (size_t)l * 2 * 1024 * 512, U, 1024, 4, 3);
    // layer 3's scan output is the head input (no LN) -> write xl directly
    u16* xo = (l == L_DIM - 1) ? xl : x_buf;
    sru_scan<<<dim3(1000, 2), 256, 0, stream>>>(U, sru_v + l * 1024,
                                                sru_b + l * 1024, xo);
  }
  gemm_bf16<<<dim3(8 * 4 * 98), 256, 0, stream>>>(xl, W1T, hbuf, 512, 2, 2);
  head_kernel<<<M_TOK / 4, 256, 0, stream>>>(hbuf, b1, bn_g, bn_b, bn_mean,
                                             bn_var, W2, b2, (float*)d_out);
}

// Round 6
// 2136.614 us; speedup vs baseline: 1.3682x; 1.3682x over previous
//
#include <hip/hip_runtime.h>
#include <stdint.h>

// ---- problem constants ----
#define T_DIM 100
#define B_DIM 1000
#define E_DIM 512
#define D_DIM 256
#define L_DIM 4
#define M_TOK (T_DIM * B_DIM)   // 100000 tokens
#define M_PAD 100096             // 782 * 128 (GEMM M padding; pad rows zeroed)
#define K_DIM 512
#define MT128 782                // m-tiles of 128 rows

typedef unsigned short u16;
typedef __bf16 bf16x8 __attribute__((ext_vector_type(8)));
typedef float f32x4 __attribute__((ext_vector_type(4)));
typedef unsigned short ushort8 __attribute__((ext_vector_type(8)));
typedef unsigned short ushort4v __attribute__((ext_vector_type(4)));

__device__ __forceinline__ u16 f2bf(float f) {
  unsigned int u = __builtin_bit_cast(unsigned int, f);
  u += 0x7fffu + ((u >> 16) & 1u);
  return (u16)(u >> 16);
}
__device__ __forceinline__ float bf2f(u16 h) {
  unsigned int u = ((unsigned int)h) << 16;
  return __builtin_bit_cast(float, u);
}

__device__ __forceinline__ void gld16(const u16* g, u16* l) {
  __builtin_amdgcn_global_load_lds(
      (const __attribute__((address_space(1))) unsigned int*)g,
      (__attribute__((address_space(3))) unsigned int*)l, 16, 0, 0);
}

// ---- transpose + cast weights: in fp32 (S, R, C) -> out bf16 (S, C, R) ----
// perm4: output-row permutation n' = (n&255)*4 + (n>>8) so GEMM columns are
// (d, gate) interleaved; sru reads one coalesced ushort4 per (t,b,d) step.
__global__ void transpose_cast(const float* __restrict__ in, u16* __restrict__ out,
                               int R, int C, int perm4) {
  __shared__ float t[32][33];
  const int s = blockIdx.z;
  const float* ib = in + (size_t)s * R * C;
  u16* ob = out + (size_t)s * R * C;
  const int c0 = blockIdx.x * 32, r0 = blockIdx.y * 32;
  const int tx = threadIdx.x, ty = threadIdx.y;  // (32, 8)
#pragma unroll
  for (int j = 0; j < 4; ++j)
    t[ty + j * 8][tx] = ib[(size_t)(r0 + ty + j * 8) * C + c0 + tx];
  __syncthreads();
#pragma unroll
  for (int j = 0; j < 4; ++j) {
    const int cc = c0 + ty + j * 8;
    const int n = perm4 ? ((cc & 255) * 4 + (cc >> 8)) : cc;
    ob[(size_t)n * R + r0 + tx] = f2bf(t[tx][ty + j * 8]);
  }
}

// ---- zero GEMM pad rows of xl (rows M_TOK..M_PAD-1), once per call ----
__global__ __launch_bounds__(256) void zero_pad(u16* __restrict__ xl) {
  const int i = blockIdx.x * 256 + threadIdx.x;  // 6144 lanes x 8 elems
  ushort8 z = {0, 0, 0, 0, 0, 0, 0, 0};
  *(ushort8*)(xl + (size_t)M_TOK * 512 + (size_t)i * 8) = z;
}

// ---- fused LayerNorm + cast to bf16 (layer 0 input only) ----
__global__ __launch_bounds__(256) void ln_cast_kernel(
    const float* __restrict__ x, const float* __restrict__ g,
    const float* __restrict__ b, u16* __restrict__ out) {
  const int wid = threadIdx.x >> 6, lane = threadIdx.x & 63;
  const int row = blockIdx.x * 4 + wid;  // < M_TOK
  const float* xr = x + (size_t)row * E_DIM + lane * 8;
  const float4 a = *(const float4*)xr;
  const float4 c = *(const float4*)(xr + 4);
  float xe[8] = {a.x, a.y, a.z, a.w, c.x, c.y, c.z, c.w};
  float s = 0.f, q = 0.f;
#pragma unroll
  for (int u = 0; u < 8; ++u) { s += xe[u]; q += xe[u] * xe[u]; }
#pragma unroll
  for (int off = 32; off; off >>= 1) {
    s += __shfl_xor(s, off, 64);
    q += __shfl_xor(q, off, 64);
  }
  const float mean = s * (1.0f / 512.0f);
  const float var = q * (1.0f / 512.0f) - mean * mean;
  const float rstd = rsqrtf(var + 1e-5f);
  const float4 g0 = *(const float4*)(g + lane * 8);
  const float4 g1 = *(const float4*)(g + lane * 8 + 4);
  const float4 b0 = *(const float4*)(b + lane * 8);
  const float4 b1v = *(const float4*)(b + lane * 8 + 4);
  float ge[8] = {g0.x, g0.y, g0.z, g0.w, g1.x, g1.y, g1.z, g1.w};
  float be[8] = {b0.x, b0.y, b0.z, b0.w, b1v.x, b1v.y, b1v.z, b1v.w};
  ushort8 o;
#pragma unroll
  for (int u = 0; u < 8; ++u)
    o[u] = f2bf((xe[u] - mean) * rstd * ge[u] + be[u]);
  *(ushort8*)(out + (size_t)row * E_DIM + lane * 8) = o;
}

// ---- 128x128 bf16 MFMA GEMM: C[z] = A @ B[z]^T ----
// EXACT round-3 kernel (proven passing, 305 us, FETCH 97 MB, 0 conflicts):
// 4 waves, 64x64/wave, chunk-XOR LDS swizzle, XCD m-tile ownership,
// 2-buffer counted pipeline (STAGE(t+1) before reads; one vmcnt(0)+barrier
// per tile), scalar C epilogue.
__global__ __launch_bounds__(256, 4) void gemm_bf16(
    const u16* __restrict__ A, const u16* __restrict__ B, u16* __restrict__ C,
    int N, int nc_shift, int ncol_shift) {
  __shared__ u16 As[2][4096];  // 16 KiB: [buf][128 rows x 32 cols swizzled]
  __shared__ u16 Bs[2][4096];  // 16 KiB

  const int bid = blockIdx.x;
  const int xcd = bid & 7;
  const int kk = bid >> 3;
  const int cix = kk & ((1 << nc_shift) - 1);   // (z, n-tile) combined
  const int jj = kk >> nc_shift;
  const int mt = xcd + 8 * jj;
  if (mt >= MT128) return;  // whole block exits before any barrier
  const int z = cix >> ncol_shift;
  const int n0 = (cix & ((1 << ncol_shift) - 1)) << 7;

  const int tid = threadIdx.x;
  const int wave = tid >> 6, lane = tid & 63;
  const int wm = wave >> 1, wn = wave & 1;

  const int r_l = lane >> 2;
  const int c_ld = (lane & 3) ^ ((lane >> 3) & 3);
  const u16* Ag = A + ((size_t)mt * 128 + wave * 32 + r_l) * K_DIM + c_ld * 8;
  const u16* Bg = B + ((size_t)z * N + n0 + wave * 32 + r_l) * K_DIM + c_ld * 8;

  auto STAGE = [&](int t) {
    u16* al = &As[t & 1][wave * 1024];
    u16* bl = &Bs[t & 1][wave * 1024];
    const u16* ag = Ag + t * 32;
    const u16* bg = Bg + t * 32;
    gld16(ag, al);
    gld16(ag + 16 * K_DIM, al + 512);
    gld16(bg, bl);
    gld16(bg + 16 * K_DIM, bl + 512);
  };

  STAGE(0);

  f32x4 acc[4][4] = {};
  const int rA = lane & 15;
  const int sw = ((lane >> 4) ^ ((rA >> 1) & 3)) * 8;  // swizzled k-chunk
  const int offA = (wm * 64 + rA) * 32 + sw;
  const int offB = (wn * 64 + rA) * 32 + sw;

  asm volatile("s_waitcnt vmcnt(0)" ::: "memory");  // tile 0 (own loads)
  asm volatile("s_barrier" ::: "memory");           // all waves' loads landed

#pragma unroll
  for (int t = 0; t < 16; ++t) {
    if (t < 15) STAGE(t + 1);  // into buf[(t+1)&1]; reads of t-1 long done
    const u16* Ab = As[t & 1];
    bf16x8 af[4], bfr[4];
#pragma unroll
    for (int mi = 0; mi < 4; ++mi)
      af[mi] = *(const bf16x8*)&Ab[offA + mi * 512];
#pragma unroll
    for (int ni = 0; ni < 4; ++ni)
      bfr[ni] = *(const bf16x8*)&Bs[t & 1][offB + ni * 512];
#pragma unroll
    for (int mi = 0; mi < 4; ++mi)
#pragma unroll
      for (int ni = 0; ni < 4; ++ni)
        acc[mi][ni] = __builtin_amdgcn_mfma_f32_16x16x32_bf16(
            af[mi], bfr[ni], acc[mi][ni], 0, 0, 0);
    if (t < 15) {
      // tile t+1's 4 loads were issued ~1 tile ago: counted-in-time wait
      asm volatile("s_waitcnt vmcnt(0)" ::: "memory");
      asm volatile("s_barrier" ::: "memory");
    }
  }

  // epilogue: verified C/D mapping (col=lane&15, row=(lane>>4)*4+r)
  u16* Cb = C + (size_t)z * M_PAD * N;
  const int rr = (lane >> 4) * 4;
  const int cc = lane & 15;
#pragma unroll
  for (int mi = 0; mi < 4; ++mi) {
#pragma unroll
    for (int ni = 0; ni < 4; ++ni) {
      const size_t row = (size_t)mt * 128 + wm * 64 + mi * 16 + rr;
      const int col = n0 + wn * 64 + ni * 16 + cc;
#pragma unroll
      for (int r = 0; r < 4; ++r)
        Cb[(row + r) * N + col] = f2bf(acc[mi][ni][r]);
    }
  }
}

// ---- fused SRU scan (both dirs) + next-layer LayerNorm, one block per b ----
// 512 threads: dir = tid>>8, d = tid&255. Scan writes h into LDS [100][520];
// depth-5 register prefetch (100 = 20x5, all indices static) keeps ~5
// outstanding 8B loads/lane to cover HBM latency. After one barrier, 8 waves
// LayerNorm the 100 rows from LDS and write xl directly. Saves the x_buf
// write + re-read (200 MB/layer).
__global__ __launch_bounds__(512) void sru_scan_ln(
    const u16* __restrict__ U, const float* __restrict__ v,
    const float* __restrict__ bb, const float* __restrict__ g,
    const float* __restrict__ b, u16* __restrict__ xl) {
  __shared__ u16 hl[T_DIM * 520];  // 104,000 B
  const int tid = threadIdx.x;
  const int d = tid & 255;
  const int dir = tid >> 8;
  const int bidx = blockIdx.x;  // batch element
  const float vf = v[(dir * 2 + 0) * 256 + d];
  const float vr = v[(dir * 2 + 1) * 256 + d];
  const float bf = bb[(dir * 2 + 0) * 256 + d];
  const float br = bb[(dir * 2 + 1) * 256 + d];
  const u16* Ud = U + (size_t)dir * M_PAD * 1024;
  const int t0 = dir ? (T_DIM - 1) : 0;
  const long step = dir ? -(long)(B_DIM * 1024) : (long)(B_DIM * 1024);
  const size_t base0 = ((size_t)t0 * B_DIM + bidx) * 1024 + d * 4;

  auto LD = [&](int idx) {
    return *(const ushort4v*)(Ud + (size_t)((long)base0 + step * (long)idx));
  };

  ushort4v pf[5];
#pragma unroll
  for (int j = 0; j < 5; ++j) pf[j] = LD(j);

  float c = 0.f;
  for (int sb = 0; sb < T_DIM; sb += 5) {
#pragma unroll
    for (int j = 0; j < 5; ++j) {
      const int s = sb + j;
      const ushort4v uv = pf[j];
      if (sb + 5 + j < T_DIM) pf[j] = LD(sb + 5 + j);
      const float u0 = bf2f(uv.x);
      const float u1 = bf2f(uv.y);
      const float u2 = bf2f(uv.z);
      const float u3 = bf2f(uv.w);
      const float f = 1.f / (1.f + __expf(-(u1 + vf * c + bf)));
      c = f * c + (1.f - f) * u0;
      const float r = 1.f / (1.f + __expf(-(u2 + vr * c + br)));
      const float h = r * c + (1.f - r) * u3;
      const int t = dir ? (T_DIM - 1 - s) : s;
      hl[t * 520 + dir * 256 + d] = f2bf(h);
    }
  }
  __syncthreads();

  // LayerNorm phase: 8 waves, wave w handles rows w, w+8, ...
  const int lane = tid & 63, w = tid >> 6;
  const float4 g0 = *(const float4*)(g + lane * 8);
  const float4 g1 = *(const float4*)(g + lane * 8 + 4);
  const float4 b0 = *(const float4*)(b + lane * 8);
  const float4 b1v = *(const float4*)(b + lane * 8 + 4);
  const float ge[8] = {g0.x, g0.y, g0.z, g0.w, g1.x, g1.y, g1.z, g1.w};
  const float be[8] = {b0.x, b0.y, b0.z, b0.w, b1v.x, b1v.y, b1v.z, b1v.w};
  for (int row = w; row < T_DIM; row += 8) {
    const ushort8 hv = *(const ushort8*)&hl[row * 520 + lane * 8];
    float xe[8];
#pragma unroll
    for (int u = 0; u < 8; ++u) xe[u] = bf2f(hv[u]);
    float s = 0.f, q = 0.f;
#pragma unroll
    for (int u = 0; u < 8; ++u) { s += xe[u]; q += xe[u] * xe[u]; }
#pragma unroll
    for (int off = 32; off; off >>= 1) {
      s += __shfl_xor(s, off, 64);
      q += __shfl_xor(q, off, 64);
    }
    const float mean = s * (1.0f / 512.0f);
    const float var = q * (1.0f / 512.0f) - mean * mean;
    const float rstd = rsqrtf(var + 1e-5f);
    ushort8 o;
#pragma unroll
    for (int u = 0; u < 8; ++u)
      o[u] = f2bf((xe[u] - mean) * rstd * ge[u] + be[u]);
    *(ushort8*)(xl + ((size_t)row * B_DIM + bidx) * 512 + lane * 8) = o;
  }
}

// ---- plain SRU scan (last layer, no LN after) ----
__global__ __launch_bounds__(256) void sru_scan(const u16* __restrict__ U,
                                                const float* __restrict__ v,
                                                const float* __restrict__ bb,
                                                u16* __restrict__ xout) {
  const int d = threadIdx.x;       // 0..255
  const int b = blockIdx.x;        // 0..999
  const int dir = blockIdx.y;      // 0..1
  const float vf = v[(dir * 2 + 0) * 256 + d];
  const float vr = v[(dir * 2 + 1) * 256 + d];
  const float bf = bb[(dir * 2 + 0) * 256 + d];
  const float br = bb[(dir * 2 + 1) * 256 + d];
  const u16* Ud = U + (size_t)dir * M_PAD * 1024;
  float c = 0.f;
  const int t0 = dir ? (T_DIM - 1) : 0;
  const long step = dir ? -(long)(B_DIM * 1024) : (long)(B_DIM * 1024);
  const size_t base0 = ((size_t)t0 * B_DIM + b) * 1024 + d * 4;
  ushort4v uv = *(const ushort4v*)(Ud + base0);
  for (int s = 0; s < T_DIM; ++s) {
    ushort4v nx = uv;
    if (s + 1 < T_DIM)
      nx = *(const ushort4v*)(Ud + (size_t)((long)base0 + step * (s + 1)));
    const int t = dir ? (T_DIM - 1 - s) : s;
    const float u0 = bf2f(uv.x);
    const float u1 = bf2f(uv.y);
    const float u2 = bf2f(uv.z);
    const float u3 = bf2f(uv.w);
    const float f = 1.f / (1.f + __expf(-(u1 + vf * c + bf)));
    c = f * c + (1.f - f) * u0;
    const float r = 1.f / (1.f + __expf(-(u2 + vr * c + br)));
    const float h = r * c + (1.f - r) * u3;
    xout[((size_t)t * B_DIM + b) * 512 + dir * 256 + d] = f2bf(h);
    uv = nx;
  }
}

// ---- head: bias + BN(eval) + ReLU + W2 + log_softmax, one wave per token ----
__global__ __launch_bounds__(256) void head_kernel(
    const u16* __restrict__ h, const float* __restrict__ b1,
    const float* __restrict__ bn_g, const float* __restrict__ bn_b,
    const float* __restrict__ bn_mean, const float* __restrict__ bn_var,
    const float* __restrict__ W2, const float* __restrict__ b2,
    float* __restrict__ out) {
  const int wid = threadIdx.x >> 6, lane = threadIdx.x & 63;
  const int row = blockIdx.x * 4 + wid;  // < 100000 (grid=25000)
  const u16* hr = h + (size_t)row * E_DIM + lane * 8;
  const ushort8 hv = *(const ushort8*)hr;
  float s0 = 0.f, s1 = 0.f, s2 = 0.f, s3 = 0.f;
  const int j0 = lane * 8;
#pragma unroll
  for (int u = 0; u < 8; ++u) {
    const int j = j0 + u;
    const float hb = bf2f(hv[u]) + b1[j];
    float hn = (hb - bn_mean[j]) * rsqrtf(bn_var[j] + 1e-5f) * bn_g[j] + bn_b[j];
    hn = fmaxf(hn, 0.f);
    const float4 w = *(const float4*)(W2 + j * 4);
    s0 += hn * w.x; s1 += hn * w.y; s2 += hn * w.z; s3 += hn * w.w;
  }
#pragma unroll
  for (int off = 32; off; off >>= 1) {
    s0 += __shfl_xor(s0, off, 64);
    s1 += __shfl_xor(s1, off, 64);
    s2 += __shfl_xor(s2, off, 64);
    s3 += __shfl_xor(s3, off, 64);
  }
  if (lane == 0) {
    const float4 bv = *(const float4*)b2;
    const float l0 = s0 + bv.x, l1 = s1 + bv.y, l2 = s2 + bv.z, l3 = s3 + bv.w;
    const float mx = fmaxf(fmaxf(l0, l1), fmaxf(l2, l3));
    const float lse =
        mx + logf(__expf(l0 - mx) + __expf(l1 - mx) + __expf(l2 - mx) + __expf(l3 - mx));
    float4 o = {l0 - lse, l1 - lse, l2 - lse, l3 - lse};
    *(float4*)(out + (size_t)row * 4) = o;
  }
}

extern "C" void kernel_launch(void* const* d_in, const int* in_sizes, int n_in,
                              void* d_out, int out_size, void* d_ws, size_t ws_size,
                              hipStream_t stream) {
  const float* sentence = (const float*)d_in[0];
  const float* sru_W = (const float*)d_in[1];
  const float* sru_v = (const float*)d_in[2];
  const float* sru_b = (const float*)d_in[3];
  const float* ln_g = (const float*)d_in[4];
  const float* ln_b = (const float*)d_in[5];
  const float* W1 = (const float*)d_in[6];
  const float* b1 = (const float*)d_in[7];
  const float* bn_g = (const float*)d_in[8];
  const float* bn_b = (const float*)d_in[9];
  const float* bn_mean = (const float*)d_in[10];
  const float* bn_var = (const float*)d_in[11];
  const float* W2 = (const float*)d_in[12];
  const float* b2 = (const float*)d_in[13];

  // workspace layout (~624 MB)
  char* ws = (char*)d_ws;
  const size_t XL_OFF = 0;                                   // bf16 xl
  const size_t X_OFF = XL_OFF + (size_t)M_PAD * 512 * 2;     // (spare)
  const size_t U_OFF = X_OFF + (size_t)M_TOK * 512 * 2;      // bf16 U
  const size_t WT_OFF = U_OFF + (size_t)2 * M_PAD * 1024 * 2;   // bf16 WT
  const size_t W1T_OFF = WT_OFF + (size_t)8 * 512 * 1024 * 2;   // bf16 W1T
  u16* xl = (u16*)(ws + XL_OFF);
  u16* U = (u16*)(ws + U_OFF);
  u16* WT = (u16*)(ws + WT_OFF);
  u16* W1T = (u16*)(ws + W1T_OFF);
  u16* hbuf = U;  // head GEMM output aliases U (dead by then)

  // weights -> bf16 transposed (N, K); sru weights N-permuted to (d,gate);
  // zero xl pad rows once
  transpose_cast<<<dim3(32, 16, 8), dim3(32, 8), 0, stream>>>(sru_W, WT, 512, 1024, 1);
  transpose_cast<<<dim3(16, 16, 1), dim3(32, 8), 0, stream>>>(W1, W1T, 512, 512, 0);
  zero_pad<<<24, 256, 0, stream>>>(xl);

  // layer-0 LN on the raw sentence
  ln_cast_kernel<<<M_TOK / 4, 256, 0, stream>>>(sentence, ln_g, ln_b, xl);

  for (int l = 0; l < L_DIM; ++l) {
    // 8 xcd x 16 (z,n) x 98 m-slots = 12544 blocks (32 idle-guarded)
    gemm_bf16<<<dim3(8 * 16 * 98), 256, 0, stream>>>(
        xl, WT + (size_t)l * 2 * 1024 * 512, U, 1024, 4, 3);
    if (l < L_DIM - 1) {
      // scan + LayerNorm of layer l+1, fused; writes xl directly
      sru_scan_ln<<<B_DIM, 512, 0, stream>>>(
          U, sru_v + l * 1024, sru_b + l * 1024,
          ln_g + (l + 1) * 512, ln_b + (l + 1) * 512, xl);
    } else {
      // last layer: scan output is the head input (no LN)
      sru_scan<<<dim3(B_DIM, 2), 256, 0, stream>>>(
          U, sru_v + l * 1024, sru_b + l * 1024, xl);
    }
  }
  gemm_bf16<<<dim3(8 * 4 * 98), 256, 0, stream>>>(xl, W1T, hbuf, 512, 2, 2);
  head_kernel<<<M_TOK / 4, 256, 0, stream>>>(hbuf, b1, bn_g, bn_b, bn_mean,
                                             bn_var, W2, b2, (float*)d_out);
}